// Round 1
// baseline (128.015 us; speedup 1.0000x reference)
//
#include <hip/hip_runtime.h>
#include <hip/hip_bf16.h>

// SimpleRetention: B=8, SEQ=2048, HIDDEN=512, HEAD=64, CHUNK=256, GAMMA=0.96875
// Pipeline: prep (W^T bf16 + xpos tables) -> proj (X@W + xpos, MFMA bf16)
//           -> attn (banded QK^T * decay @ V, MFMA bf16)

typedef __attribute__((ext_vector_type(8))) short short8;
typedef __attribute__((ext_vector_type(4))) float floatx4;

#define LOG2GAMMA (-0.04580350f)  // log2(0.96875)

static __device__ __forceinline__ unsigned short f2bf(float f) {
    __hip_bfloat16 h = __float2bfloat16(f);
    return *reinterpret_cast<unsigned short*>(&h);
}

// ---------------------------------------------------------------------------
// Kernel 0: W transpose->bf16  +  xpos cos/sin*scale tables
// Wt layout: [192][512] bf16, rows 0-63 = W_Q cols, 64-127 = W_K, 128-191 = W_V
// tabs: 4 tables of [2048][32] f32: 0=cosQ 1=sinQ 2=cosK 3=sinK
// ---------------------------------------------------------------------------
__global__ __launch_bounds__(256) void prep_kernel(
    const float* __restrict__ Wq, const float* __restrict__ Wk,
    const float* __restrict__ Wv,
    __hip_bfloat16* __restrict__ Wt, float* __restrict__ tabs)
{
    int idx = blockIdx.x * 256 + threadIdx.x;
    const int WT_N = 192 * 512;
    if (idx < WT_N) {
        int n = idx >> 9, k = idx & 511;
        int m = n >> 6, c = n & 63;
        const float* W = (m == 0) ? Wq : ((m == 1) ? Wk : Wv);
        Wt[idx] = __float2bfloat16(W[k * 64 + c]);
    } else {
        int t2 = idx - WT_N;
        if (t2 < 4 * 2048 * 32) {
            int tab = t2 >> 16;          // 0..3
            int rem = t2 & 65535;
            int pos = rem >> 5;          // 0..2047
            int t   = rem & 31;          // 0..31
            float inv_freq = powf(10000.0f, -(float)t / 32.0f);
            float sinus = (float)pos * inv_freq;
            float s = sinf(sinus), c = cosf(sinus);
            float sv = (2.0f * (float)t + 0.4f * 64.0f) / (1.4f * 64.0f);
            float power = (float)pos / 512.0f;
            float scl = powf(sv, (tab >= 2) ? -power : power);
            tabs[t2] = ((tab & 1) == 0) ? c * scl : s * scl;
        }
    }
}

// ---------------------------------------------------------------------------
// Kernel 1: projections. 256 blocks x 64 rows. MFMA 16x16x32 bf16.
// Each wave: 16 rows x 192 cols (12 n-tiles). K tiled by 128.
// LDS rows padded: 128 bf16 data -> 136 (68 dwords == 4 mod 32: 2-way = free)
// Epilogue: xpos via shfl_xor(1) partner; Q,K -> [b][n][64] bf16, V -> [b][64][n]
// ---------------------------------------------------------------------------
__global__ __launch_bounds__(256) void proj_kernel(
    const float* __restrict__ X, const __hip_bfloat16* __restrict__ Wt,
    const float* __restrict__ tabs,
    __hip_bfloat16* __restrict__ Qb, __hip_bfloat16* __restrict__ Kb,
    __hip_bfloat16* __restrict__ Vt)
{
    __shared__ __hip_bfloat16 lx[64][136];
    __shared__ __hip_bfloat16 lw[192][136];

    int tid = threadIdx.x;
    int r0 = blockIdx.x * 64;                 // global row base (b*2048+n)
    int w = tid >> 6, lane = tid & 63, quad = lane >> 4, l15 = lane & 15;

    floatx4 acc[12];
#pragma unroll
    for (int t = 0; t < 12; t++) acc[t] = (floatx4){0.f, 0.f, 0.f, 0.f};

    for (int kb = 0; kb < 4; kb++) {
        // stage X tile 64x128 f32 -> bf16 LDS
#pragma unroll
        for (int u = 0; u < 8; u++) {
            int f = u * 256 + tid;
            int row = f >> 5, c = f & 31;     // 32 float4 per row
            float4 v = *(const float4*)(X + (r0 + row) * 512 + kb * 128 + c * 4);
            ushort4 pk;
            pk.x = f2bf(v.x); pk.y = f2bf(v.y); pk.z = f2bf(v.z); pk.w = f2bf(v.w);
            *(ushort4*)&lx[row][c * 4] = pk;
        }
        // stage Wt tile 192x128 bf16
#pragma unroll
        for (int u = 0; u < 12; u++) {
            int f = u * 256 + tid;
            int row = f >> 4, c = f & 15;     // 16 uint4 per row
            uint4 v = *(const uint4*)(Wt + row * 512 + kb * 128 + c * 8);
            *(uint4*)&lw[row][c * 8] = v;
        }
        __syncthreads();
#pragma unroll
        for (int ks = 0; ks < 4; ks++) {
            short8 a = *(const short8*)&lx[w * 16 + l15][ks * 32 + quad * 8];
#pragma unroll
            for (int t = 0; t < 12; t++) {
                short8 bfr = *(const short8*)&lw[t * 16 + l15][ks * 32 + quad * 8];
                acc[t] = __builtin_amdgcn_mfma_f32_16x16x32_bf16(a, bfr, acc[t], 0, 0, 0);
            }
        }
        __syncthreads();
    }

    // epilogue: C/D layout col = l15 (n-tile), row = quad*4+rg
    int rbase = r0 + w * 16 + quad * 4;
#pragma unroll
    for (int rg = 0; rg < 4; rg++) {
        int r = rbase + rg;
        int b = r >> 11, n = r & 2047;
        // Q tiles 0..3: xpos upscale
#pragma unroll
        for (int t = 0; t < 4; t++) {
            float val = acc[t][rg];
            float prt = __shfl_xor(val, 1, 64);   // lane^1 == col^1, same row
            int ch = t * 16 + l15;
            int tt = ch >> 1;
            float co = tabs[n * 32 + tt];
            float si = tabs[65536 + n * 32 + tt];
            float o = (l15 & 1) ? (val * co + prt * si) : (val * co - prt * si);
            Qb[(b * 2048 + n) * 64 + ch] = __float2bfloat16(o);
        }
        // K tiles 4..7: xpos downscale
#pragma unroll
        for (int t = 4; t < 8; t++) {
            float val = acc[t][rg];
            float prt = __shfl_xor(val, 1, 64);
            int ch = (t - 4) * 16 + l15;
            int tt = ch >> 1;
            float co = tabs[131072 + n * 32 + tt];
            float si = tabs[196608 + n * 32 + tt];
            float o = (l15 & 1) ? (val * co + prt * si) : (val * co - prt * si);
            Kb[(b * 2048 + n) * 64 + ch] = __float2bfloat16(o);
        }
        // V tiles 8..11: store transposed [b][dim][n]
#pragma unroll
        for (int t = 8; t < 12; t++) {
            int ch = (t - 8) * 16 + l15;
            Vt[(b * 64 + ch) * 2048 + n] = __float2bfloat16(acc[t][rg]);
        }
    }
}

// ---------------------------------------------------------------------------
// Kernel 2: banded retention. 256 blocks = (b, 64-row q tile).
// KV chunks qc-3..qc (gamma^768 ~ 2.6e-11 << threshold).
// Wave: 16 q rows. S = Q K^T (Q frags in regs), P = S*gamma^|i-j| -> LDS (bf16),
// out += P V via Vt. LDS rows padded to stride == 4 mod 32 dwords (2-way free).
// ---------------------------------------------------------------------------
__global__ __launch_bounds__(256) void attn_kernel(
    const __hip_bfloat16* __restrict__ Qb, const __hip_bfloat16* __restrict__ Kb,
    const __hip_bfloat16* __restrict__ Vt, float* __restrict__ out)
{
    __shared__ __hip_bfloat16 lk[256][72];       // 64 data + 8 pad
    __shared__ __hip_bfloat16 lv[64][264];       // 256 data + 8 pad
    __shared__ __hip_bfloat16 lp[4][16][264];    // per-wave P

    int tid = threadIdx.x;
    int b = blockIdx.x >> 5, qsub = blockIdx.x & 31;
    int q0 = qsub * 64, qc = qsub >> 2;
    int w = tid >> 6, lane = tid & 63, quad = lane >> 4, l15 = lane & 15;

    // Q A-fragments for this wave's 16 rows, kept in registers
    short8 qf[2];
#pragma unroll
    for (int kk = 0; kk < 2; kk++)
        qf[kk] = *(const short8*)(Qb + (b * 2048 + q0 + w * 16 + l15) * 64 + kk * 32 + quad * 8);

    floatx4 o[4];
#pragma unroll
    for (int t = 0; t < 4; t++) o[t] = (floatx4){0.f, 0.f, 0.f, 0.f};

    int kc0 = (qc >= 3) ? (qc - 3) : 0;
    for (int kc = kc0; kc <= qc; kc++) {
        int kbase = kc * 256;
        // stage K chunk 256x64
#pragma unroll
        for (int u = 0; u < 8; u++) {
            int f = u * 256 + tid;
            int row = f >> 3, c = f & 7;         // 8 uint4 per row
            *(uint4*)&lk[row][c * 8] =
                *(const uint4*)(Kb + (b * 2048 + kbase + row) * 64 + c * 8);
        }
        // stage Vt chunk 64x256
#pragma unroll
        for (int u = 0; u < 8; u++) {
            int f = u * 256 + tid;
            int row = f >> 5, c = f & 31;        // 32 uint4 per row
            *(uint4*)&lv[row][c * 8] =
                *(const uint4*)(Vt + (b * 64 + row) * 2048 + kbase + c * 8);
        }
        __syncthreads();

        // S = Q K^T : 16 key-tiles x 2 k-steps
        floatx4 s[16];
#pragma unroll
        for (int t = 0; t < 16; t++) s[t] = (floatx4){0.f, 0.f, 0.f, 0.f};
#pragma unroll
        for (int t = 0; t < 16; t++) {
#pragma unroll
            for (int kk = 0; kk < 2; kk++) {
                short8 bfr = *(const short8*)&lk[t * 16 + l15][kk * 32 + quad * 8];
                s[t] = __builtin_amdgcn_mfma_f32_16x16x32_bf16(qf[kk], bfr, s[t], 0, 0, 0);
            }
        }

        // decay, cast to bf16, write P (C-layout -> row-major LDS)
        int i0 = q0 + w * 16 + quad * 4;
#pragma unroll
        for (int t = 0; t < 16; t++) {
            int j = kbase + t * 16 + l15;
#pragma unroll
            for (int rg = 0; rg < 4; rg++) {
                int d = i0 + rg - j; d = (d < 0) ? -d : d;
                float p = s[t][rg] * exp2f(LOG2GAMMA * (float)d);
                lp[w][quad * 4 + rg][t * 16 + l15] = __float2bfloat16(p);
            }
        }
        __syncthreads();

        // out += P V  (A = P from LDS, B = Vt rows)
#pragma unroll
        for (int ks = 0; ks < 8; ks++) {
            short8 a = *(const short8*)&lp[w][l15][ks * 32 + quad * 8];
#pragma unroll
            for (int t2 = 0; t2 < 4; t2++) {
                short8 bfr = *(const short8*)&lv[t2 * 16 + l15][ks * 32 + quad * 8];
                o[t2] = __builtin_amdgcn_mfma_f32_16x16x32_bf16(a, bfr, o[t2], 0, 0, 0);
            }
        }
        __syncthreads();
    }

    // write out f32, coalesced 64B per 16 lanes
    int rbase = b * 2048 + q0 + w * 16 + quad * 4;
#pragma unroll
    for (int t2 = 0; t2 < 4; t2++)
#pragma unroll
        for (int rg = 0; rg < 4; rg++)
            out[(rbase + rg) * 64 + t2 * 16 + l15] = o[t2][rg];
}

// ---------------------------------------------------------------------------
extern "C" void kernel_launch(void* const* d_in, const int* in_sizes, int n_in,
                              void* d_out, int out_size, void* d_ws, size_t ws_size,
                              hipStream_t stream) {
    const float* X  = (const float*)d_in[0];
    const float* Wq = (const float*)d_in[1];
    const float* Wk = (const float*)d_in[2];
    const float* Wv = (const float*)d_in[3];
    float* out = (float*)d_out;

    char* ws = (char*)d_ws;
    __hip_bfloat16* Wt   = (__hip_bfloat16*)(ws);                 // 192*512*2   = 196608
    float*          tabs = (float*)(ws + 196608);                 // 4*65536*4   = 1048576
    __hip_bfloat16* Qb   = (__hip_bfloat16*)(ws + 1245184);       // 8*2048*64*2 = 2097152
    __hip_bfloat16* Kb   = (__hip_bfloat16*)(ws + 3342336);       // 2097152
    __hip_bfloat16* Vt   = (__hip_bfloat16*)(ws + 5439488);       // 2097152 (ends 7536640)

    prep_kernel<<<1408, 256, 0, stream>>>(Wq, Wk, Wv, Wt, tabs);
    proj_kernel<<<256, 256, 0, stream>>>(X, Wt, tabs, Qb, Kb, Vt);
    attn_kernel<<<256, 256, 0, stream>>>(Qb, Kb, Vt, out);
}

// Round 2
// 125.737 us; speedup vs baseline: 1.0181x; 1.0181x over previous
//
#include <hip/hip_runtime.h>
#include <hip/hip_bf16.h>

// SimpleRetention: B=8, SEQ=2048, HIDDEN=512, HEAD=64, CHUNK=256, GAMMA=0.96875
// v2: occupancy-focused. proj: 512 blocks/32 rows, 2 blocks/CU, LDS V transpose.
//     attn: 512 blocks/32 q-rows, no V staging (L2 direct), 3 blocks/CU.

typedef __attribute__((ext_vector_type(8))) short short8;
typedef __attribute__((ext_vector_type(4))) float floatx4;

#define LOG2GAMMA (-0.04580350f)  // log2(0.96875)

static __device__ __forceinline__ unsigned short f2bf(float f) {
    __hip_bfloat16 h = __float2bfloat16(f);
    return *reinterpret_cast<unsigned short*>(&h);
}

// ---------------------------------------------------------------------------
// Kernel 0: W transpose->bf16  +  xpos cos/sin*scale tables
// Wt layout: [192][512] bf16, rows 0-63 = W_Q cols, 64-127 = W_K, 128-191 = W_V
// tabs: 4 tables of [2048][32] f32: 0=cosQ 1=sinQ 2=cosK 3=sinK
// ---------------------------------------------------------------------------
__global__ __launch_bounds__(256) void prep_kernel(
    const float* __restrict__ Wq, const float* __restrict__ Wk,
    const float* __restrict__ Wv,
    __hip_bfloat16* __restrict__ Wt, float* __restrict__ tabs)
{
    int idx = blockIdx.x * 256 + threadIdx.x;
    const int WT_N = 192 * 512;
    if (idx < WT_N) {
        int n = idx >> 9, k = idx & 511;
        int m = n >> 6, c = n & 63;
        const float* W = (m == 0) ? Wq : ((m == 1) ? Wk : Wv);
        Wt[idx] = __float2bfloat16(W[k * 64 + c]);
    } else {
        int t2 = idx - WT_N;
        if (t2 < 4 * 2048 * 32) {
            int tab = t2 >> 16;          // 0..3
            int rem = t2 & 65535;
            int pos = rem >> 5;          // 0..2047
            int t   = rem & 31;          // 0..31
            float inv_freq = powf(10000.0f, -(float)t / 32.0f);
            float sinus = (float)pos * inv_freq;
            float s = sinf(sinus), c = cosf(sinus);
            float sv = (2.0f * (float)t + 0.4f * 64.0f) / (1.4f * 64.0f);
            float power = (float)pos / 512.0f;
            float scl = powf(sv, (tab >= 2) ? -power : power);
            tabs[t2] = ((tab & 1) == 0) ? c * scl : s * scl;
        }
    }
}

// ---------------------------------------------------------------------------
// Kernel 1: projections. 512 blocks x 32 rows. MFMA 16x16x32 bf16.
// Wave (rh, nh): rows rh*16..+15, n-tiles nh*6..+5. LDS ~60KB -> 2 blocks/CU.
// Epilogue: xpos via shfl_xor(1); V transposed through LDS (reuse lx) so the
// Vt[b][dim][n] store is coalesced uint4 instead of a 2-B scatter.
// ---------------------------------------------------------------------------
__global__ __launch_bounds__(256, 2) void proj_kernel(
    const float* __restrict__ X, const __hip_bfloat16* __restrict__ Wt,
    const float* __restrict__ tabs,
    __hip_bfloat16* __restrict__ Qb, __hip_bfloat16* __restrict__ Kb,
    __hip_bfloat16* __restrict__ Vt)
{
    __shared__ __hip_bfloat16 lx[32][136];    // 8.7 KB (reused as lvt[64][40])
    __shared__ __hip_bfloat16 lw[192][136];   // 51 KB

    int tid = threadIdx.x;
    int r0 = blockIdx.x * 32;                 // global row base (b*2048+n)
    int w = tid >> 6, lane = tid & 63, quad = lane >> 4, l15 = lane & 15;
    int rh = w & 1, nh = w >> 1;

    floatx4 acc[6];
#pragma unroll
    for (int t = 0; t < 6; t++) acc[t] = (floatx4){0.f, 0.f, 0.f, 0.f};

    for (int kb = 0; kb < 4; kb++) {
        // stage X tile 32x128 f32 -> bf16 LDS (4 float4 per thread)
#pragma unroll
        for (int u = 0; u < 4; u++) {
            int f = u * 256 + tid;
            int row = f >> 5, c = f & 31;
            float4 v = *(const float4*)(X + (r0 + row) * 512 + kb * 128 + c * 4);
            ushort4 pk;
            pk.x = f2bf(v.x); pk.y = f2bf(v.y); pk.z = f2bf(v.z); pk.w = f2bf(v.w);
            *(ushort4*)&lx[row][c * 4] = pk;
        }
        // stage Wt tile 192x128 bf16 (12 uint4 per thread)
#pragma unroll
        for (int u = 0; u < 12; u++) {
            int f = u * 256 + tid;
            int row = f >> 4, c = f & 15;
            uint4 v = *(const uint4*)(Wt + row * 512 + kb * 128 + c * 8);
            *(uint4*)&lw[row][c * 8] = v;
        }
        __syncthreads();
#pragma unroll
        for (int ks = 0; ks < 4; ks++) {
            short8 a = *(const short8*)&lx[rh * 16 + l15][ks * 32 + quad * 8];
#pragma unroll
            for (int t = 0; t < 6; t++) {
                short8 bfr = *(const short8*)&lw[(nh * 6 + t) * 16 + l15][ks * 32 + quad * 8];
                acc[t] = __builtin_amdgcn_mfma_f32_16x16x32_bf16(a, bfr, acc[t], 0, 0, 0);
            }
        }
        __syncthreads();
    }

    // ---- epilogue. C/D layout: col = l15, row = quad*4+rg ----
    int b0 = r0 >> 11, n0 = r0 & 2047;
    int rbase = r0 + rh * 16 + quad * 4;

    // 1) nh==1 waves stash V tiles (t=8..11) transposed into LDS (reuse lx)
    __hip_bfloat16* lvt = &lx[0][0];          // treat as [64][40]
    if (nh == 1) {
#pragma unroll
        for (int tl = 2; tl < 6; tl++) {      // t = 8..11
            int ch = (tl - 2) * 16 + l15;
#pragma unroll
            for (int rg = 0; rg < 4; rg++)
                lvt[ch * 40 + rh * 16 + quad * 4 + rg] = __float2bfloat16(acc[tl][rg]);
        }
    }
    __syncthreads();

    // 2) Q/K xpos stores
#pragma unroll
    for (int tl = 0; tl < 6; tl++) {
        int t = nh * 6 + tl;
        if (t >= 8) break;                    // V handled via LDS
#pragma unroll
        for (int rg = 0; rg < 4; rg++) {
            int r = rbase + rg;
            int b = r >> 11, n = r & 2047;
            float val = acc[tl][rg];
            float prt = __shfl_xor(val, 1, 64);   // lane^1 == col^1, same row
            if (t < 4) {
                int ch = t * 16 + l15;
                int tt = ch >> 1;
                float co = tabs[n * 32 + tt];
                float si = tabs[65536 + n * 32 + tt];
                float o = (l15 & 1) ? (val * co + prt * si) : (val * co - prt * si);
                Qb[(b * 2048 + n) * 64 + ch] = __float2bfloat16(o);
            } else {
                int ch = (t - 4) * 16 + l15;
                int tt = ch >> 1;
                float co = tabs[131072 + n * 32 + tt];
                float si = tabs[196608 + n * 32 + tt];
                float o = (l15 & 1) ? (val * co + prt * si) : (val * co - prt * si);
                Kb[(b * 2048 + n) * 64 + ch] = __float2bfloat16(o);
            }
        }
    }

    // 3) cooperative coalesced Vt store: 64 dims x 32 n, one uint4 per thread
    {
        int row = tid >> 2, c = tid & 3;
        uint4 v = *(const uint4*)&lvt[row * 40 + c * 8];
        *(uint4*)(Vt + ((size_t)(b0 * 64 + row)) * 2048 + n0 + c * 8) = v;
    }
}

// ---------------------------------------------------------------------------
// Kernel 2: banded retention. 512 blocks = (b, 32-row q tile), 4 waves.
// Wave (rh, ph): QK for kv-tiles ph*8..+7 on rows rh*16..+15; decay -> shared
// P (bf16); PV with A from P-LDS over all 256 keys, B-frags direct from L2 Vt,
// output v-tiles ph*2, ph*2+1. LDS 53 KB -> 3 blocks/CU.
// KV chunks qc-3..qc (gamma^768 ~ 2.6e-11 << threshold).
// ---------------------------------------------------------------------------
__global__ __launch_bounds__(256, 3) void attn_kernel(
    const __hip_bfloat16* __restrict__ Qb, const __hip_bfloat16* __restrict__ Kb,
    const __hip_bfloat16* __restrict__ Vt, float* __restrict__ out)
{
    __shared__ __hip_bfloat16 lk[256][72];    // 36 KB
    __shared__ __hip_bfloat16 lp[32][264];    // 16.9 KB shared P

    int tid = threadIdx.x;
    int b = blockIdx.x >> 6, qt = blockIdx.x & 63;
    int q0 = qt * 32, qc = q0 >> 8;
    int w = tid >> 6, lane = tid & 63, quad = lane >> 4, l15 = lane & 15;
    int rh = w & 1, ph = w >> 1;

    // Q A-fragments for this wave's 16 rows, kept in registers
    short8 qf[2];
#pragma unroll
    for (int kk = 0; kk < 2; kk++)
        qf[kk] = *(const short8*)(Qb + ((size_t)(b * 2048 + q0 + rh * 16 + l15)) * 64 + kk * 32 + quad * 8);

    const __hip_bfloat16* vbase = Vt + (size_t)b * 64 * 2048;

    floatx4 o[2];
    o[0] = (floatx4){0.f, 0.f, 0.f, 0.f};
    o[1] = (floatx4){0.f, 0.f, 0.f, 0.f};

    int kc0 = (qc >= 3) ? (qc - 3) : 0;
    for (int kc = kc0; kc <= qc; kc++) {
        int kbase = kc * 256;
        // stage K chunk 256x64 bf16 (8 uint4 per thread, fully coalesced)
#pragma unroll
        for (int u = 0; u < 8; u++) {
            int f = u * 256 + tid;
            int row = f >> 3, c = f & 7;
            *(uint4*)&lk[row][c * 8] =
                *(const uint4*)(Kb + ((size_t)(b * 2048 + kbase + row)) * 64 + c * 8);
        }
        __syncthreads();

        // S = Q K^T for this wave's 8 kv-tiles
        floatx4 s[8];
#pragma unroll
        for (int t = 0; t < 8; t++) s[t] = (floatx4){0.f, 0.f, 0.f, 0.f};
#pragma unroll
        for (int t = 0; t < 8; t++) {
#pragma unroll
            for (int kk = 0; kk < 2; kk++) {
                short8 bfr = *(const short8*)&lk[(ph * 8 + t) * 16 + l15][kk * 32 + quad * 8];
                s[t] = __builtin_amdgcn_mfma_f32_16x16x32_bf16(qf[kk], bfr, s[t], 0, 0, 0);
            }
        }

        // decay, cast bf16, write P (C-layout -> row-major shared LDS)
        int i0 = q0 + rh * 16 + quad * 4;
#pragma unroll
        for (int t = 0; t < 8; t++) {
            int j = kbase + (ph * 8 + t) * 16 + l15;
#pragma unroll
            for (int rg = 0; rg < 4; rg++) {
                int d = i0 + rg - j; d = (d < 0) ? -d : d;
                float p = s[t][rg] * exp2f(LOG2GAMMA * (float)d);
                lp[rh * 16 + quad * 4 + rg][(ph * 8 + t) * 16 + l15] = __float2bfloat16(p);
            }
        }
        __syncthreads();

        // out += P V : A from shared P, B-frags direct from L2-resident Vt
#pragma unroll
        for (int ks = 0; ks < 8; ks++) {
            short8 a = *(const short8*)&lp[rh * 16 + l15][ks * 32 + quad * 8];
#pragma unroll
            for (int tt = 0; tt < 2; tt++) {
                int t2 = ph * 2 + tt;
                short8 bfr = *(const short8*)(vbase + ((size_t)(t2 * 16 + l15)) * 2048
                                              + kbase + ks * 32 + quad * 8);
                o[tt] = __builtin_amdgcn_mfma_f32_16x16x32_bf16(a, bfr, o[tt], 0, 0, 0);
            }
        }
        // next iteration's K staging only touches lk (all lk readers passed the
        // post-decay barrier); PV reads lp, staged writes are disjoint -> safe.
    }

    // write out f32, coalesced 64B per quad-row
    int rbase = b * 2048 + q0 + rh * 16 + quad * 4;
#pragma unroll
    for (int tt = 0; tt < 2; tt++)
#pragma unroll
        for (int rg = 0; rg < 4; rg++)
            out[((size_t)(rbase + rg)) * 64 + (ph * 2 + tt) * 16 + l15] = o[tt][rg];
}

// ---------------------------------------------------------------------------
extern "C" void kernel_launch(void* const* d_in, const int* in_sizes, int n_in,
                              void* d_out, int out_size, void* d_ws, size_t ws_size,
                              hipStream_t stream) {
    const float* X  = (const float*)d_in[0];
    const float* Wq = (const float*)d_in[1];
    const float* Wk = (const float*)d_in[2];
    const float* Wv = (const float*)d_in[3];
    float* out = (float*)d_out;

    char* ws = (char*)d_ws;
    __hip_bfloat16* Wt   = (__hip_bfloat16*)(ws);                 // 192*512*2   = 196608
    float*          tabs = (float*)(ws + 196608);                 // 4*65536*4   = 1048576
    __hip_bfloat16* Qb   = (__hip_bfloat16*)(ws + 1245184);       // 8*2048*64*2 = 2097152
    __hip_bfloat16* Kb   = (__hip_bfloat16*)(ws + 3342336);       // 2097152
    __hip_bfloat16* Vt   = (__hip_bfloat16*)(ws + 5439488);       // 2097152 (ends 7536640)

    prep_kernel<<<1408, 256, 0, stream>>>(Wq, Wk, Wv, Wt, tabs);
    proj_kernel<<<512, 256, 0, stream>>>(X, Wt, tabs, Qb, Kb, Vt);
    attn_kernel<<<512, 256, 0, stream>>>(Qb, Kb, Vt, out);
}